// Round 6
// baseline (491.308 us; speedup 1.0000x reference)
//
#include <hip/hip_runtime.h>
#include <math.h>

// ---------------------------------------------------------------------------
// SplineConv GNN, 3 layers, K=5, dim=2, mean aggr, root+bias, ReLU, FC+sigmoid.
//
// Round 6: rounds 3 and 5 pinned the edge kernels at ~115us regardless of
// 2x changes in LDS bytes and VALU ops. The invariant: E coalesced 64B-line
// f32 atomics -> WRITE_SIZE 100MB/dispatch at ~890 GB/s (atomics execute past
// L2 at the device-coherent point). Fix: build dst-CSR once (hist+scan+
// scatter of packed edge records), then each layer is ONE fused kernel:
// 16 lanes per dst node loop its in-edges, accumulate in REGISTERS, apply
// mean+root+bias+relu, store f16. No atomics, no agg buffer, no memsets,
// no finalize dispatches. Inner math + LDS geometry = round 3/5 proven
// (k*320 + o*20 dword rows, f16 pairs, fdot2).
// ---------------------------------------------------------------------------

#define KS 5

typedef _Float16 h2f __attribute__((ext_vector_type(2)));

__device__ __forceinline__ h2f u2h(unsigned u) { return __builtin_bit_cast(h2f, u); }

#if __has_builtin(__builtin_amdgcn_fdot2)
__device__ __forceinline__ float fdot2(h2f a, h2f b, float c) {
    return __builtin_amdgcn_fdot2(a, b, c, false);
}
#else
__device__ __forceinline__ float fdot2(h2f a, h2f b, float c) {
    return c + (float)a[0] * (float)b[0] + (float)a[1] * (float)b[1];
}
#endif

// ---- CSR build --------------------------------------------------------------
__global__ void hist_kernel(const int* __restrict__ dst, int* __restrict__ cnt, int E) {
    int stride = gridDim.x * blockDim.x;
    for (int e = blockIdx.x * blockDim.x + threadIdx.x; e < E; e += stride)
        atomicAdd(&cnt[dst[e]], 1);
}

#define SCAN_T 256
#define SCAN_E 1024  // elements per scan block (4 per thread)

__global__ void scan1_kernel(const int* __restrict__ cnt, int* __restrict__ offs,
                             int* __restrict__ sums, int N) {
    __shared__ int sh[SCAN_T];
    int base = blockIdx.x * SCAN_E + threadIdx.x * 4;
    int v[4];
    int s = 0;
    #pragma unroll
    for (int j = 0; j < 4; ++j) { v[j] = (base + j < N) ? cnt[base + j] : 0; s += v[j]; }
    sh[threadIdx.x] = s;
    __syncthreads();
    for (int off = 1; off < SCAN_T; off <<= 1) {
        int t = (threadIdx.x >= off) ? sh[threadIdx.x - off] : 0;
        __syncthreads();
        sh[threadIdx.x] += t;
        __syncthreads();
    }
    int run = (threadIdx.x > 0) ? sh[threadIdx.x - 1] : 0;
    #pragma unroll
    for (int j = 0; j < 4; ++j) {
        if (base + j < N) offs[base + j] = run;
        run += v[j];
    }
    if (threadIdx.x == SCAN_T - 1) sums[blockIdx.x] = sh[SCAN_T - 1];
}

__global__ void scan2_kernel(int* __restrict__ sums, int nb) {
    __shared__ int sh[SCAN_T];
    int v = (threadIdx.x < nb) ? sums[threadIdx.x] : 0;
    sh[threadIdx.x] = v;
    __syncthreads();
    for (int off = 1; off < SCAN_T; off <<= 1) {
        int t = (threadIdx.x >= off) ? sh[threadIdx.x - off] : 0;
        __syncthreads();
        sh[threadIdx.x] += t;
        __syncthreads();
    }
    if (threadIdx.x < nb) sums[threadIdx.x] = (threadIdx.x > 0) ? sh[threadIdx.x - 1] : 0;
}

__global__ void scan3_kernel(int* __restrict__ offs, const int* __restrict__ sums,
                             int N, int E) {
    int i = blockIdx.x * blockDim.x + threadIdx.x;
    if (i < N) offs[i] += sums[i >> 10];
    if (i == 0) offs[N] = E;
}

// scatter packed edge record to CSR position.
// pk = { wi0|wi1<<8|wi2<<16|wi3<<24, f32(f0), f32(f1), src }
__global__ void scatter_kernel(const float* __restrict__ eattr, const int* __restrict__ src,
                               const int* __restrict__ dst, const int* __restrict__ offs,
                               int* __restrict__ cursor, uint4* __restrict__ epack, int E) {
    int stride = gridDim.x * blockDim.x;
    for (int e = blockIdx.x * blockDim.x + threadIdx.x; e < E; e += stride) {
        float2 ea = reinterpret_cast<const float2*>(eattr)[e];
        float a0 = ea.x * (float)(KS - 1);
        float a1 = ea.y * (float)(KS - 1);
        float k0 = fminf(fmaxf(floorf(a0), 0.0f), (float)(KS - 2));
        float k1 = fminf(fmaxf(floorf(a1), 0.0f), (float)(KS - 2));
        float f0 = a0 - k0, f1 = a1 - k1;
        int i0 = (int)k0, i1 = (int)k1;
        int w00 = i0 + KS * i1;
        unsigned wis = (unsigned)w00 | ((unsigned)(w00 + 1) << 8) |
                       ((unsigned)(w00 + KS) << 16) | ((unsigned)(w00 + KS + 1) << 24);
        int d = dst[e];
        int r = atomicAdd(&cursor[d], 1);
        epack[offs[d] + r] = make_uint4(wis, __float_as_uint(f0), __float_as_uint(f1),
                                        (unsigned)src[e]);
    }
}

__device__ __forceinline__ void decode_pk(uint4 pk, int& s, float b[4], int wi[4]) {
    s = (int)pk.w;
    wi[0] = (int)(pk.x & 255); wi[1] = (int)((pk.x >> 8) & 255);
    wi[2] = (int)((pk.x >> 16) & 255); wi[3] = (int)(pk.x >> 24);
    float f0 = __uint_as_float(pk.y);
    float f1 = __uint_as_float(pk.z);
    float g0 = 1.0f - f0, g1 = 1.0f - f1;
    b[0] = g0 * g1; b[1] = f0 * g1; b[2] = g0 * f1; b[3] = f0 * f1;
}

// ---- fused layer 1: x[N,2] f32 -> h f16, CSR aggregation, no atomics -------
__global__ __launch_bounds__(256) void csr2_kernel(
        const float* __restrict__ x,      // [N,2]
        const uint4* __restrict__ epack,  // [E] CSR-ordered
        const int* __restrict__ offs,     // [N+1]
        const float* __restrict__ W,      // [25,2,16]
        const float* __restrict__ root,   // [2,16]
        const float* __restrict__ bias,   // [16]
        ushort* __restrict__ hout,        // [N,16] f16
        int N) {
    __shared__ float Wl[25 * 96];         // row o*6 floats, k stride 96 (round-3 geometry)
    for (int idx = threadIdx.x; idx < 25 * 32; idx += blockDim.x) {
        int k = idx >> 5;
        int r = idx & 31;
        int i = r >> 4;
        int o = r & 15;
        Wl[k * 96 + o * 6 + i] = W[idx];
    }
    __syncthreads();

    int t = blockIdx.x * blockDim.x + threadIdx.x;
    if (t >= N * 16) return;
    int o = t & 15;
    int n = t >> 4;
    int row = offs[n], end = offs[n + 1];

    float acc = 0.0f;
    for (int j = row; j < end; ++j) {
        uint4 pk = epack[j];
        int s;
        float b[4];
        int wi[4];
        decode_pk(pk, s, b, wi);
        float2 xv = reinterpret_cast<const float2*>(x)[s];
        #pragma unroll
        for (int sp = 0; sp < 4; ++sp) {
            float2 w = *reinterpret_cast<const float2*>(&Wl[wi[sp] * 96 + o * 6]);
            acc += b[sp] * (xv.x * w.x + xv.y * w.y);
        }
    }
    float inv = 1.0f / fmaxf((float)(end - row), 1.0f);
    float2 xn = reinterpret_cast<const float2*>(x)[n];
    acc = acc * inv + xn.x * root[o] + xn.y * root[16 + o] + bias[o];
    hout[t] = __builtin_bit_cast(ushort, (_Float16)fmaxf(acc, 0.0f));
}

// ---- fused layers 2/3: h f16 -> h f16, CSR aggregation, no atomics ---------
__global__ __launch_bounds__(256) void csr16_kernel(
        const ushort* __restrict__ hh,    // [N,16] f16
        const uint4* __restrict__ epack,  // [E]
        const int* __restrict__ offs,     // [N+1]
        const float* __restrict__ W,      // [25,16,16] f32
        const float* __restrict__ root,   // [16,16] f32
        const float* __restrict__ bias,   // [16]
        ushort* __restrict__ hout,        // [N,16] f16
        int N) {
    __shared__ unsigned Wl[25 * 320];     // f16 pairs, row o*20 dwords (8 used), k*320
    __shared__ unsigned Rl[16 * 20];      // root, same row geometry
    {
        ushort* Ws = reinterpret_cast<ushort*>(Wl);
        for (int idx = threadIdx.x; idx < 25 * 256; idx += blockDim.x) {
            int k = idx >> 8;
            int r = idx & 255;
            int i = r >> 4;
            int o = r & 15;
            Ws[(k * 320 + o * 20) * 2 + i] = __builtin_bit_cast(ushort, (_Float16)W[idx]);
        }
        ushort* Rs = reinterpret_cast<ushort*>(Rl);
        for (int idx = threadIdx.x; idx < 256; idx += blockDim.x) {
            int i = idx >> 4;
            int o = idx & 15;
            Rs[(o * 20) * 2 + i] = __builtin_bit_cast(ushort, (_Float16)root[idx]);
        }
    }
    __syncthreads();

    int t = blockIdx.x * blockDim.x + threadIdx.x;
    if (t >= N * 16) return;
    int o = t & 15;
    int n = t >> 4;
    int row = offs[n], end = offs[n + 1];

    float acc = 0.0f;
    for (int j = row; j < end; ++j) {
        uint4 pk = epack[j];
        int s;
        float b[4];
        int wi[4];
        decode_pk(pk, s, b, wi);
        const uint4* hp = reinterpret_cast<const uint4*>(hh + (size_t)s * 16);
        uint4 ha = hp[0], hb = hp[1];
        #pragma unroll
        for (int sp = 0; sp < 4; ++sp) {
            const uint4* wp = reinterpret_cast<const uint4*>(&Wl[wi[sp] * 320 + o * 20]);
            uint4 wa = wp[0], wb = wp[1];
            float p = 0.0f;
            p = fdot2(u2h(ha.x), u2h(wa.x), p);
            p = fdot2(u2h(ha.y), u2h(wa.y), p);
            p = fdot2(u2h(ha.z), u2h(wa.z), p);
            p = fdot2(u2h(ha.w), u2h(wa.w), p);
            p = fdot2(u2h(hb.x), u2h(wb.x), p);
            p = fdot2(u2h(hb.y), u2h(wb.y), p);
            p = fdot2(u2h(hb.z), u2h(wb.z), p);
            p = fdot2(u2h(hb.w), u2h(wb.w), p);
            acc = fmaf(b[sp], p, acc);
        }
    }
    float inv = 1.0f / fmaxf((float)(end - row), 1.0f);
    acc *= inv;
    // root term on own row
    {
        const uint4* hp = reinterpret_cast<const uint4*>(hh + (size_t)n * 16);
        uint4 ha = hp[0], hb = hp[1];
        const uint4* rp = reinterpret_cast<const uint4*>(&Rl[o * 20]);
        uint4 ra = rp[0], rb = rp[1];
        float p = 0.0f;
        p = fdot2(u2h(ha.x), u2h(ra.x), p);
        p = fdot2(u2h(ha.y), u2h(ra.y), p);
        p = fdot2(u2h(ha.z), u2h(ra.z), p);
        p = fdot2(u2h(ha.w), u2h(ra.w), p);
        p = fdot2(u2h(hb.x), u2h(rb.x), p);
        p = fdot2(u2h(hb.y), u2h(rb.y), p);
        p = fdot2(u2h(hb.z), u2h(rb.z), p);
        p = fdot2(u2h(hb.w), u2h(rb.w), p);
        acc += p + bias[o];
    }
    hout[t] = __builtin_bit_cast(ushort, (_Float16)fmaxf(acc, 0.0f));
}

// ---- final FC + sigmoid ----------------------------------------------------
__global__ void fc_kernel(const ushort* __restrict__ h,  // [N,16] f16
                          const float* __restrict__ fcw, // [16]
                          const float* __restrict__ fcb, // [1]
                          float* __restrict__ out, int N) {
    int n = blockIdx.x * blockDim.x + threadIdx.x;
    if (n >= N) return;
    const uint4* hp = reinterpret_cast<const uint4*>(h + (size_t)n * 16);
    uint4 ha = hp[0], hb = hp[1];
    unsigned dw[8] = {ha.x, ha.y, ha.z, ha.w, hb.x, hb.y, hb.z, hb.w};
    float acc = fcb[0];
    #pragma unroll
    for (int j = 0; j < 8; ++j) {
        h2f p = u2h(dw[j]);
        acc += (float)p[0] * fcw[2 * j] + (float)p[1] * fcw[2 * j + 1];
    }
    out[n] = 1.0f / (1.0f + expf(-acc));
}

// ---------------------------------------------------------------------------
// Fallback path (ws too small for CSR): round-5 atomic kernels, no pack.
// ---------------------------------------------------------------------------
__global__ void deg_count_kernel(const int* __restrict__ dst, float* __restrict__ deg, int E) {
    int stride = gridDim.x * blockDim.x;
    for (int e = blockIdx.x * blockDim.x + threadIdx.x; e < E; e += stride)
        atomicAdd(&deg[dst[e]], 1.0f);
}
__global__ void deg_inv_kernel(float* __restrict__ deg, int N) {
    int i = blockIdx.x * blockDim.x + threadIdx.x;
    if (i < N) deg[i] = 1.0f / fmaxf(deg[i], 1.0f);
}
__device__ __forceinline__ void compute_basis(const float* eattr, const int* srcp, int e,
                                              int& s, float b[4], int wi[4]) {
    float2 ea = reinterpret_cast<const float2*>(eattr)[e];
    float a0 = ea.x * (float)(KS - 1);
    float a1 = ea.y * (float)(KS - 1);
    float k0 = fminf(fmaxf(floorf(a0), 0.0f), (float)(KS - 2));
    float k1 = fminf(fmaxf(floorf(a1), 0.0f), (float)(KS - 2));
    float f0 = a0 - k0, f1 = a1 - k1;
    int i0 = (int)k0, i1 = (int)k1;
    int w00 = i0 + KS * i1;
    wi[0] = w00; wi[1] = w00 + 1; wi[2] = w00 + KS; wi[3] = w00 + KS + 1;
    float g0 = 1.0f - f0, g1 = 1.0f - f1;
    b[0] = g0 * g1; b[1] = f0 * g1; b[2] = g0 * f1; b[3] = f0 * f1;
    s = srcp[e];
}
__global__ __launch_bounds__(256) void edge16h_fb(
        const ushort* __restrict__ hh, const int* __restrict__ dst,
        const float* __restrict__ eattr, const int* __restrict__ srcp,
        const float* __restrict__ W, float* __restrict__ agg, int E) {
    __shared__ unsigned Wl[25 * 320];
    {
        ushort* Ws = reinterpret_cast<ushort*>(Wl);
        for (int idx = threadIdx.x; idx < 25 * 256; idx += blockDim.x) {
            int k = idx >> 8;
            int r = idx & 255;
            int i = r >> 4;
            int o = r & 15;
            Ws[(k * 320 + o * 20) * 2 + i] = __builtin_bit_cast(ushort, (_Float16)W[idx]);
        }
    }
    __syncthreads();
    int gs = gridDim.x * blockDim.x;
    int total = E * 16;
    for (int t = blockIdx.x * blockDim.x + threadIdx.x; t < total; t += gs) {
        int e = t >> 4;
        int o = t & 15;
        int s;
        float b[4];
        int wi[4];
        compute_basis(eattr, srcp, e, s, b, wi);
        const uint4* hp = reinterpret_cast<const uint4*>(hh + (size_t)s * 16);
        uint4 ha = hp[0], hb = hp[1];
        float acc = 0.0f;
        #pragma unroll
        for (int sp = 0; sp < 4; ++sp) {
            const uint4* wp = reinterpret_cast<const uint4*>(&Wl[wi[sp] * 320 + o * 20]);
            uint4 wa = wp[0], wb = wp[1];
            float p = 0.0f;
            p = fdot2(u2h(ha.x), u2h(wa.x), p);
            p = fdot2(u2h(ha.y), u2h(wa.y), p);
            p = fdot2(u2h(ha.z), u2h(wa.z), p);
            p = fdot2(u2h(ha.w), u2h(wa.w), p);
            p = fdot2(u2h(hb.x), u2h(wb.x), p);
            p = fdot2(u2h(hb.y), u2h(wb.y), p);
            p = fdot2(u2h(hb.z), u2h(wb.z), p);
            p = fdot2(u2h(hb.w), u2h(wb.w), p);
            acc = fmaf(b[sp], p, acc);
        }
        atomicAdd(&agg[(size_t)dst[e] * 16 + o], acc);
    }
}
__global__ __launch_bounds__(256) void edge2_fb(
        const float* __restrict__ x, const int* __restrict__ dst,
        const float* __restrict__ eattr, const int* __restrict__ srcp,
        const float* __restrict__ W, float* __restrict__ agg, int E) {
    __shared__ float Wl[25 * 96];
    for (int idx = threadIdx.x; idx < 25 * 32; idx += blockDim.x) {
        int k = idx >> 5;
        int r = idx & 31;
        int i = r >> 4;
        int o = r & 15;
        Wl[k * 96 + o * 6 + i] = W[idx];
    }
    __syncthreads();
    int gs = gridDim.x * blockDim.x;
    int total = E * 16;
    for (int t = blockIdx.x * blockDim.x + threadIdx.x; t < total; t += gs) {
        int e = t >> 4;
        int o = t & 15;
        int s;
        float b[4];
        int wi[4];
        compute_basis(eattr, srcp, e, s, b, wi);
        float2 xv = reinterpret_cast<const float2*>(x)[s];
        float acc = 0.0f;
        #pragma unroll
        for (int sp = 0; sp < 4; ++sp) {
            float2 w = *reinterpret_cast<const float2*>(&Wl[wi[sp] * 96 + o * 6]);
            acc += b[sp] * (xv.x * w.x + xv.y * w.y);
        }
        atomicAdd(&agg[(size_t)dst[e] * 16 + o], acc);
    }
}
__global__ void finalize2h_fb(const float* __restrict__ x, const float* __restrict__ root,
                              const float* __restrict__ bias, const float* __restrict__ invdeg,
                              const float* __restrict__ agg, ushort* __restrict__ hout, int N) {
    int t = blockIdx.x * blockDim.x + threadIdx.x;
    if (t >= N * 16) return;
    int o = t & 15;
    int n = t >> 4;
    float2 xv = reinterpret_cast<const float2*>(x)[n];
    float acc = agg[t] * invdeg[n] + xv.x * root[o] + xv.y * root[16 + o] + bias[o];
    hout[t] = __builtin_bit_cast(ushort, (_Float16)fmaxf(acc, 0.0f));
}
__global__ void finalize16h_fb(const ushort* __restrict__ hin, const float* __restrict__ root,
                               const float* __restrict__ bias, const float* __restrict__ invdeg,
                               const float* __restrict__ agg, ushort* __restrict__ hout, int N) {
    int t = blockIdx.x * blockDim.x + threadIdx.x;
    if (t >= N * 16) return;
    int o = t & 15;
    int n = t >> 4;
    const uint4* hp = reinterpret_cast<const uint4*>(hin + (size_t)n * 16);
    uint4 ha = hp[0], hb = hp[1];
    float acc = agg[t] * invdeg[n] + bias[o];
    unsigned dw[8] = {ha.x, ha.y, ha.z, ha.w, hb.x, hb.y, hb.z, hb.w};
    #pragma unroll
    for (int j = 0; j < 8; ++j) {
        h2f p = u2h(dw[j]);
        acc += (float)p[0] * root[(2 * j) * 16 + o] + (float)p[1] * root[(2 * j + 1) * 16 + o];
    }
    hout[t] = __builtin_bit_cast(ushort, (_Float16)fmaxf(acc, 0.0f));
}

extern "C" void kernel_launch(void* const* d_in, const int* in_sizes, int n_in,
                              void* d_out, int out_size, void* d_ws, size_t ws_size,
                              hipStream_t stream) {
    const float* x      = (const float*)d_in[0];
    const int*   eidx   = (const int*)d_in[1];
    const float* eattr  = (const float*)d_in[2];
    const float* W1     = (const float*)d_in[3];
    const float* root1  = (const float*)d_in[4];
    const float* b1     = (const float*)d_in[5];
    const float* W2     = (const float*)d_in[6];
    const float* root2  = (const float*)d_in[7];
    const float* b2     = (const float*)d_in[8];
    const float* W3     = (const float*)d_in[9];
    const float* root3  = (const float*)d_in[10];
    const float* b3     = (const float*)d_in[11];
    const float* fcw    = (const float*)d_in[12];
    const float* fcb    = (const float*)d_in[13];
    float* out = (float*)d_out;

    const int N = in_sizes[0] / 2;
    const int E = in_sizes[2] / 2;
    const int* src = eidx;
    const int* dst = eidx + E;
    const int BT = 256;

    // ---- CSR workspace layout (bytes) ----
    char* w = (char*)d_ws;
    size_t off = 0;
    uint4* epack = (uint4*)(w + off); off += (size_t)E * 16;
    int* offs    = (int*)(w + off);   off += ((size_t)(N + 1)) * 4; off = (off + 15) & ~(size_t)15;
    int* cnt     = (int*)(w + off);   off += (size_t)N * 4;         off = (off + 15) & ~(size_t)15;
    int* cursor  = (int*)(w + off);   off += (size_t)N * 4;         off = (off + 15) & ~(size_t)15;
    int* sums    = (int*)(w + off);   off += SCAN_T * 4;            off = (off + 15) & ~(size_t)15;
    ushort* hH1  = (ushort*)(w + off); off += (size_t)N * 32;
    ushort* hH2  = (ushort*)(w + off); off += (size_t)N * 32;
    size_t need_csr = off;
    int nb = (N + SCAN_E - 1) / SCAN_E;

    if (ws_size >= need_csr && nb <= SCAN_T) {
        // ---- CSR build ----
        hipMemsetAsync(cnt, 0, (size_t)N * 4, stream);
        hipMemsetAsync(cursor, 0, (size_t)N * 4, stream);
        hist_kernel<<<2048, BT, 0, stream>>>(dst, cnt, E);
        scan1_kernel<<<nb, SCAN_T, 0, stream>>>(cnt, offs, sums, N);
        scan2_kernel<<<1, SCAN_T, 0, stream>>>(sums, nb);
        scan3_kernel<<<(N + BT - 1) / BT, BT, 0, stream>>>(offs, sums, N, E);
        scatter_kernel<<<2048, BT, 0, stream>>>(eattr, src, dst, offs, cursor, epack, E);

        // ---- fused layers ----
        int node_grid = (N * 16 + BT - 1) / BT;
        csr2_kernel<<<node_grid, BT, 0, stream>>>(x, epack, offs, W1, root1, b1, hH1, N);
        csr16_kernel<<<node_grid, BT, 0, stream>>>(hH1, epack, offs, W2, root2, b2, hH2, N);
        csr16_kernel<<<node_grid, BT, 0, stream>>>(hH2, epack, offs, W3, root3, b3, hH1, N);
        fc_kernel<<<(N + BT - 1) / BT, BT, 0, stream>>>(hH1, fcw, fcb, out, N);
    } else {
        // ---- fallback: round-5 atomic path, no pack ----
        float* agg = (float*)d_ws;                       // N*16
        float* deg = agg + (size_t)N * 16;               // N
        size_t f17 = ((size_t)N * 17 + 7) & ~(size_t)7;
        ushort* fH1 = (ushort*)((float*)d_ws + f17);     // N*16 f16
        ushort* fH2 = fH1 + (size_t)N * 16;
        const int EG = 2048;
        int node_grid = (N * 16 + BT - 1) / BT;

        hipMemsetAsync(deg, 0, (size_t)N * 4, stream);
        deg_count_kernel<<<2048, BT, 0, stream>>>(dst, deg, E);
        deg_inv_kernel<<<(N + BT - 1) / BT, BT, 0, stream>>>(deg, N);

        hipMemsetAsync(agg, 0, (size_t)N * 64, stream);
        edge2_fb<<<EG, BT, 0, stream>>>(x, dst, eattr, src, W1, agg, E);
        finalize2h_fb<<<node_grid, BT, 0, stream>>>(x, root1, b1, deg, agg, fH1, N);

        hipMemsetAsync(agg, 0, (size_t)N * 64, stream);
        edge16h_fb<<<EG, BT, 0, stream>>>(fH1, dst, eattr, src, W2, agg, E);
        finalize16h_fb<<<node_grid, BT, 0, stream>>>(fH1, root2, b2, deg, agg, fH2, N);

        hipMemsetAsync(agg, 0, (size_t)N * 64, stream);
        edge16h_fb<<<EG, BT, 0, stream>>>(fH2, dst, eattr, src, W3, agg, E);
        finalize16h_fb<<<node_grid, BT, 0, stream>>>(fH2, root3, b3, deg, agg, fH1, N);

        fc_kernel<<<(N + BT - 1) / BT, BT, 0, stream>>>(fH1, fcw, fcb, out, N);
    }
}

// Round 7
// 411.478 us; speedup vs baseline: 1.1940x; 1.1940x over previous
//
#include <hip/hip_runtime.h>
#include <math.h>

// ---------------------------------------------------------------------------
// SplineConv GNN, 3 layers, K=5, dim=2, mean aggr, root+bias, ReLU, FC+sigmoid.
//
// Round 7: CSR structure kept (atomics gone: WRITE_SIZE 100MB->3MB, confirmed).
// csr16's 140us was latency-starvation: padded LDS (33.3KB, 2.5x waste) capped
// occupancy at 37.7% while the per-node gather loop is dependent-load bound.
// Fix: compact XOR-swizzled LDS, zero padding:
//   slot(o,c) = (o>>2)*8 + ((2o + (o>>2) + c) & 7)   [32 16B-slots per k]
// -> per b128 read each quad-bank gets exactly 8/64 lanes (conflict-free floor),
//    W = 12.8KB + root 0.5KB => 8 blocks/CU (wave cap), occupancy ~100%.
// __launch_bounds__(256,8) caps VGPR at 64. 1-deep epack prefetch breaks the
// dependent-load chain.
// ---------------------------------------------------------------------------

#define KS 5

typedef _Float16 h2f __attribute__((ext_vector_type(2)));

__device__ __forceinline__ h2f u2h(unsigned u) { return __builtin_bit_cast(h2f, u); }

#if __has_builtin(__builtin_amdgcn_fdot2)
__device__ __forceinline__ float fdot2(h2f a, h2f b, float c) {
    return __builtin_amdgcn_fdot2(a, b, c, false);
}
#else
__device__ __forceinline__ float fdot2(h2f a, h2f b, float c) {
    return c + (float)a[0] * (float)b[0] + (float)a[1] * (float)b[1];
}
#endif

// swizzled 16B-slot index within a k-block (32 slots = 128 dwords)
__device__ __forceinline__ int wslot(int o, int c) {
    int g = o >> 2;
    return g * 8 + ((2 * o + g + c) & 7);
}

// ---- CSR build --------------------------------------------------------------
__global__ void hist_kernel(const int* __restrict__ dst, int* __restrict__ cnt, int E) {
    int stride = gridDim.x * blockDim.x;
    for (int e = blockIdx.x * blockDim.x + threadIdx.x; e < E; e += stride)
        atomicAdd(&cnt[dst[e]], 1);
}

#define SCAN_T 256
#define SCAN_E 1024  // elements per scan block (4 per thread)

__global__ void scan1_kernel(const int* __restrict__ cnt, int* __restrict__ offs,
                             int* __restrict__ sums, int N) {
    __shared__ int sh[SCAN_T];
    int base = blockIdx.x * SCAN_E + threadIdx.x * 4;
    int v[4];
    int s = 0;
    #pragma unroll
    for (int j = 0; j < 4; ++j) { v[j] = (base + j < N) ? cnt[base + j] : 0; s += v[j]; }
    sh[threadIdx.x] = s;
    __syncthreads();
    for (int off = 1; off < SCAN_T; off <<= 1) {
        int t = (threadIdx.x >= off) ? sh[threadIdx.x - off] : 0;
        __syncthreads();
        sh[threadIdx.x] += t;
        __syncthreads();
    }
    int run = (threadIdx.x > 0) ? sh[threadIdx.x - 1] : 0;
    #pragma unroll
    for (int j = 0; j < 4; ++j) {
        if (base + j < N) offs[base + j] = run;
        run += v[j];
    }
    if (threadIdx.x == SCAN_T - 1) sums[blockIdx.x] = sh[SCAN_T - 1];
}

__global__ void scan2_kernel(int* __restrict__ sums, int nb) {
    __shared__ int sh[SCAN_T];
    int v = (threadIdx.x < nb) ? sums[threadIdx.x] : 0;
    sh[threadIdx.x] = v;
    __syncthreads();
    for (int off = 1; off < SCAN_T; off <<= 1) {
        int t = (threadIdx.x >= off) ? sh[threadIdx.x - off] : 0;
        __syncthreads();
        sh[threadIdx.x] += t;
        __syncthreads();
    }
    if (threadIdx.x < nb) sums[threadIdx.x] = (threadIdx.x > 0) ? sh[threadIdx.x - 1] : 0;
}

__global__ void scan3_kernel(int* __restrict__ offs, const int* __restrict__ sums,
                             int N, int E) {
    int i = blockIdx.x * blockDim.x + threadIdx.x;
    if (i < N) offs[i] += sums[i >> 10];
    if (i == 0) offs[N] = E;
}

// scatter packed edge record to CSR position.
// pk = { wi0|wi1<<8|wi2<<16|wi3<<24, f32(f0), f32(f1), src }
__global__ void scatter_kernel(const float* __restrict__ eattr, const int* __restrict__ src,
                               const int* __restrict__ dst, const int* __restrict__ offs,
                               int* __restrict__ cursor, uint4* __restrict__ epack, int E) {
    int stride = gridDim.x * blockDim.x;
    for (int e = blockIdx.x * blockDim.x + threadIdx.x; e < E; e += stride) {
        float2 ea = reinterpret_cast<const float2*>(eattr)[e];
        float a0 = ea.x * (float)(KS - 1);
        float a1 = ea.y * (float)(KS - 1);
        float k0 = fminf(fmaxf(floorf(a0), 0.0f), (float)(KS - 2));
        float k1 = fminf(fmaxf(floorf(a1), 0.0f), (float)(KS - 2));
        float f0 = a0 - k0, f1 = a1 - k1;
        int i0 = (int)k0, i1 = (int)k1;
        int w00 = i0 + KS * i1;
        unsigned wis = (unsigned)w00 | ((unsigned)(w00 + 1) << 8) |
                       ((unsigned)(w00 + KS) << 16) | ((unsigned)(w00 + KS + 1) << 24);
        int d = dst[e];
        int r = atomicAdd(&cursor[d], 1);
        epack[offs[d] + r] = make_uint4(wis, __float_as_uint(f0), __float_as_uint(f1),
                                        (unsigned)src[e]);
    }
}

__device__ __forceinline__ void decode_pk(uint4 pk, int& s, float b[4], int wi[4]) {
    s = (int)pk.w;
    wi[0] = (int)(pk.x & 255); wi[1] = (int)((pk.x >> 8) & 255);
    wi[2] = (int)((pk.x >> 16) & 255); wi[3] = (int)(pk.x >> 24);
    float f0 = __uint_as_float(pk.y);
    float f1 = __uint_as_float(pk.z);
    float g0 = 1.0f - f0, g1 = 1.0f - f1;
    b[0] = g0 * g1; b[1] = f0 * g1; b[2] = g0 * f1; b[3] = f0 * f1;
}

// ---- fused layer 1: x[N,2] f32 -> h f16, CSR aggregation, no atomics -------
__global__ __launch_bounds__(256, 8) void csr2_kernel(
        const float* __restrict__ x,      // [N,2]
        const uint4* __restrict__ epack,  // [E] CSR-ordered
        const int* __restrict__ offs,     // [N+1]
        const float* __restrict__ W,      // [25,2,16]
        const float* __restrict__ root,   // [2,16]
        const float* __restrict__ bias,   // [16]
        ushort* __restrict__ hout,        // [N,16] f16
        int N) {
    __shared__ float Wl[25 * 32];         // compact [k][o] float2, 3.2KB
    for (int idx = threadIdx.x; idx < 25 * 32; idx += blockDim.x) {
        int k = idx >> 5;
        int r = idx & 31;
        int i = r >> 4;
        int o = r & 15;
        Wl[k * 32 + o * 2 + i] = W[idx];
    }
    __syncthreads();

    int t = blockIdx.x * blockDim.x + threadIdx.x;
    if (t >= N * 16) return;
    int o = t & 15;
    int n = t >> 4;
    int row = offs[n], end = offs[n + 1];

    float acc = 0.0f;
    uint4 pk = epack[(row < end) ? row : 0];
    for (int j = row; j < end; ++j) {
        uint4 cur = pk;
        int jn = j + 1;
        pk = epack[(jn < end) ? jn : j];
        int s;
        float b[4];
        int wi[4];
        decode_pk(cur, s, b, wi);
        float2 xv = reinterpret_cast<const float2*>(x)[s];
        #pragma unroll
        for (int sp = 0; sp < 4; ++sp) {
            float2 w = *reinterpret_cast<const float2*>(&Wl[wi[sp] * 32 + o * 2]);
            acc += b[sp] * (xv.x * w.x + xv.y * w.y);
        }
    }
    float inv = 1.0f / fmaxf((float)(end - row), 1.0f);
    float2 xn = reinterpret_cast<const float2*>(x)[n];
    acc = acc * inv + xn.x * root[o] + xn.y * root[16 + o] + bias[o];
    hout[t] = __builtin_bit_cast(ushort, (_Float16)fmaxf(acc, 0.0f));
}

// ---- fused layers 2/3: h f16 -> h f16, CSR aggregation, no atomics ---------
__global__ __launch_bounds__(256, 8) void csr16_kernel(
        const ushort* __restrict__ hh,    // [N,16] f16
        const uint4* __restrict__ epack,  // [E]
        const int* __restrict__ offs,     // [N+1]
        const float* __restrict__ W,      // [25,16,16] f32
        const float* __restrict__ root,   // [16,16] f32
        const float* __restrict__ bias,   // [16]
        ushort* __restrict__ hout,        // [N,16] f16
        int N) {
    __shared__ unsigned Wl[25 * 128];     // compact swizzled f16 pairs, 12.8KB
    __shared__ unsigned Rl[128];          // root, same swizzle, 0.5KB
    {
        ushort* Ws = reinterpret_cast<ushort*>(Wl);
        for (int idx = threadIdx.x; idx < 25 * 256; idx += blockDim.x) {
            int k = idx >> 8;
            int r = idx & 255;
            int i = r >> 4;
            int o = r & 15;
            Ws[k * 256 + wslot(o, i >> 3) * 8 + (i & 7)] =
                __builtin_bit_cast(ushort, (_Float16)W[idx]);
        }
        ushort* Rs = reinterpret_cast<ushort*>(Rl);
        for (int idx = threadIdx.x; idx < 256; idx += blockDim.x) {
            int i = idx >> 4;
            int o = idx & 15;
            Rs[wslot(o, i >> 3) * 8 + (i & 7)] =
                __builtin_bit_cast(ushort, (_Float16)root[idx]);
        }
    }
    __syncthreads();

    int t = blockIdx.x * blockDim.x + threadIdx.x;
    if (t >= N * 16) return;
    int o = t & 15;
    int n = t >> 4;
    int row = offs[n], end = offs[n + 1];
    int s0 = wslot(o, 0) * 4;             // dword offsets, constant per thread
    int s1 = wslot(o, 1) * 4;

    float acc = 0.0f;
    uint4 pk = epack[(row < end) ? row : 0];
    for (int j = row; j < end; ++j) {
        uint4 cur = pk;
        int jn = j + 1;
        pk = epack[(jn < end) ? jn : j];
        int s;
        float b[4];
        int wi[4];
        decode_pk(cur, s, b, wi);
        const uint4* hp = reinterpret_cast<const uint4*>(hh + (size_t)s * 16);
        uint4 ha = hp[0], hb = hp[1];
        #pragma unroll
        for (int sp = 0; sp < 4; ++sp) {
            int kb = wi[sp] * 128;
            uint4 wa = *reinterpret_cast<const uint4*>(&Wl[kb + s0]);
            uint4 wb = *reinterpret_cast<const uint4*>(&Wl[kb + s1]);
            float p = 0.0f;
            p = fdot2(u2h(ha.x), u2h(wa.x), p);
            p = fdot2(u2h(ha.y), u2h(wa.y), p);
            p = fdot2(u2h(ha.z), u2h(wa.z), p);
            p = fdot2(u2h(ha.w), u2h(wa.w), p);
            p = fdot2(u2h(hb.x), u2h(wb.x), p);
            p = fdot2(u2h(hb.y), u2h(wb.y), p);
            p = fdot2(u2h(hb.z), u2h(wb.z), p);
            p = fdot2(u2h(hb.w), u2h(wb.w), p);
            acc = fmaf(b[sp], p, acc);
        }
    }
    float inv = 1.0f / fmaxf((float)(end - row), 1.0f);
    acc *= inv;
    // root term on own row
    {
        const uint4* hp = reinterpret_cast<const uint4*>(hh + (size_t)n * 16);
        uint4 ha = hp[0], hb = hp[1];
        uint4 ra = *reinterpret_cast<const uint4*>(&Rl[s0]);
        uint4 rb = *reinterpret_cast<const uint4*>(&Rl[s1]);
        float p = 0.0f;
        p = fdot2(u2h(ha.x), u2h(ra.x), p);
        p = fdot2(u2h(ha.y), u2h(ra.y), p);
        p = fdot2(u2h(ha.z), u2h(ra.z), p);
        p = fdot2(u2h(ha.w), u2h(ra.w), p);
        p = fdot2(u2h(hb.x), u2h(rb.x), p);
        p = fdot2(u2h(hb.y), u2h(rb.y), p);
        p = fdot2(u2h(hb.z), u2h(rb.z), p);
        p = fdot2(u2h(hb.w), u2h(rb.w), p);
        acc += p + bias[o];
    }
    hout[t] = __builtin_bit_cast(ushort, (_Float16)fmaxf(acc, 0.0f));
}

// ---- final FC + sigmoid ----------------------------------------------------
__global__ void fc_kernel(const ushort* __restrict__ h,  // [N,16] f16
                          const float* __restrict__ fcw, // [16]
                          const float* __restrict__ fcb, // [1]
                          float* __restrict__ out, int N) {
    int n = blockIdx.x * blockDim.x + threadIdx.x;
    if (n >= N) return;
    const uint4* hp = reinterpret_cast<const uint4*>(h + (size_t)n * 16);
    uint4 ha = hp[0], hb = hp[1];
    unsigned dw[8] = {ha.x, ha.y, ha.z, ha.w, hb.x, hb.y, hb.z, hb.w};
    float acc = fcb[0];
    #pragma unroll
    for (int j = 0; j < 8; ++j) {
        h2f p = u2h(dw[j]);
        acc += (float)p[0] * fcw[2 * j] + (float)p[1] * fcw[2 * j + 1];
    }
    out[n] = 1.0f / (1.0f + expf(-acc));
}

// ---------------------------------------------------------------------------
// Fallback path (ws too small for CSR): round-5 atomic kernels.
// ---------------------------------------------------------------------------
__global__ void deg_count_kernel(const int* __restrict__ dst, float* __restrict__ deg, int E) {
    int stride = gridDim.x * blockDim.x;
    for (int e = blockIdx.x * blockDim.x + threadIdx.x; e < E; e += stride)
        atomicAdd(&deg[dst[e]], 1.0f);
}
__global__ void deg_inv_kernel(float* __restrict__ deg, int N) {
    int i = blockIdx.x * blockDim.x + threadIdx.x;
    if (i < N) deg[i] = 1.0f / fmaxf(deg[i], 1.0f);
}
__device__ __forceinline__ void compute_basis(const float* eattr, const int* srcp, int e,
                                              int& s, float b[4], int wi[4]) {
    float2 ea = reinterpret_cast<const float2*>(eattr)[e];
    float a0 = ea.x * (float)(KS - 1);
    float a1 = ea.y * (float)(KS - 1);
    float k0 = fminf(fmaxf(floorf(a0), 0.0f), (float)(KS - 2));
    float k1 = fminf(fmaxf(floorf(a1), 0.0f), (float)(KS - 2));
    float f0 = a0 - k0, f1 = a1 - k1;
    int i0 = (int)k0, i1 = (int)k1;
    int w00 = i0 + KS * i1;
    wi[0] = w00; wi[1] = w00 + 1; wi[2] = w00 + KS; wi[3] = w00 + KS + 1;
    float g0 = 1.0f - f0, g1 = 1.0f - f1;
    b[0] = g0 * g1; b[1] = f0 * g1; b[2] = g0 * f1; b[3] = f0 * f1;
    s = srcp[e];
}
__global__ __launch_bounds__(256) void edge16h_fb(
        const ushort* __restrict__ hh, const int* __restrict__ dst,
        const float* __restrict__ eattr, const int* __restrict__ srcp,
        const float* __restrict__ W, float* __restrict__ agg, int E) {
    __shared__ unsigned Wl[25 * 128];
    {
        ushort* Ws = reinterpret_cast<ushort*>(Wl);
        for (int idx = threadIdx.x; idx < 25 * 256; idx += blockDim.x) {
            int k = idx >> 8;
            int r = idx & 255;
            int i = r >> 4;
            int o = r & 15;
            Ws[k * 256 + wslot(o, i >> 3) * 8 + (i & 7)] =
                __builtin_bit_cast(ushort, (_Float16)W[idx]);
        }
    }
    __syncthreads();
    int gs = gridDim.x * blockDim.x;
    int total = E * 16;
    for (int t = blockIdx.x * blockDim.x + threadIdx.x; t < total; t += gs) {
        int e = t >> 4;
        int o = t & 15;
        int s;
        float b[4];
        int wi[4];
        compute_basis(eattr, srcp, e, s, b, wi);
        int s0 = wslot(o, 0) * 4, s1 = wslot(o, 1) * 4;
        const uint4* hp = reinterpret_cast<const uint4*>(hh + (size_t)s * 16);
        uint4 ha = hp[0], hb = hp[1];
        float acc = 0.0f;
        #pragma unroll
        for (int sp = 0; sp < 4; ++sp) {
            int kb = wi[sp] * 128;
            uint4 wa = *reinterpret_cast<const uint4*>(&Wl[kb + s0]);
            uint4 wb = *reinterpret_cast<const uint4*>(&Wl[kb + s1]);
            float p = 0.0f;
            p = fdot2(u2h(ha.x), u2h(wa.x), p);
            p = fdot2(u2h(ha.y), u2h(wa.y), p);
            p = fdot2(u2h(ha.z), u2h(wa.z), p);
            p = fdot2(u2h(ha.w), u2h(wa.w), p);
            p = fdot2(u2h(hb.x), u2h(wb.x), p);
            p = fdot2(u2h(hb.y), u2h(wb.y), p);
            p = fdot2(u2h(hb.z), u2h(wb.z), p);
            p = fdot2(u2h(hb.w), u2h(wb.w), p);
            acc = fmaf(b[sp], p, acc);
        }
        atomicAdd(&agg[(size_t)dst[e] * 16 + o], acc);
    }
}
__global__ __launch_bounds__(256) void edge2_fb(
        const float* __restrict__ x, const int* __restrict__ dst,
        const float* __restrict__ eattr, const int* __restrict__ srcp,
        const float* __restrict__ W, float* __restrict__ agg, int E) {
    __shared__ float Wl[25 * 32];
    for (int idx = threadIdx.x; idx < 25 * 32; idx += blockDim.x) {
        int k = idx >> 5;
        int r = idx & 31;
        int i = r >> 4;
        int o = r & 15;
        Wl[k * 32 + o * 2 + i] = W[idx];
    }
    __syncthreads();
    int gs = gridDim.x * blockDim.x;
    int total = E * 16;
    for (int t = blockIdx.x * blockDim.x + threadIdx.x; t < total; t += gs) {
        int e = t >> 4;
        int o = t & 15;
        int s;
        float b[4];
        int wi[4];
        compute_basis(eattr, srcp, e, s, b, wi);
        float2 xv = reinterpret_cast<const float2*>(x)[s];
        float acc = 0.0f;
        #pragma unroll
        for (int sp = 0; sp < 4; ++sp) {
            float2 w = *reinterpret_cast<const float2*>(&Wl[wi[sp] * 32 + o * 2]);
            acc += b[sp] * (xv.x * w.x + xv.y * w.y);
        }
        atomicAdd(&agg[(size_t)dst[e] * 16 + o], acc);
    }
}
__global__ void finalize2h_fb(const float* __restrict__ x, const float* __restrict__ root,
                              const float* __restrict__ bias, const float* __restrict__ invdeg,
                              const float* __restrict__ agg, ushort* __restrict__ hout, int N) {
    int t = blockIdx.x * blockDim.x + threadIdx.x;
    if (t >= N * 16) return;
    int o = t & 15;
    int n = t >> 4;
    float2 xv = reinterpret_cast<const float2*>(x)[n];
    float acc = agg[t] * invdeg[n] + xv.x * root[o] + xv.y * root[16 + o] + bias[o];
    hout[t] = __builtin_bit_cast(ushort, (_Float16)fmaxf(acc, 0.0f));
}
__global__ void finalize16h_fb(const ushort* __restrict__ hin, const float* __restrict__ root,
                               const float* __restrict__ bias, const float* __restrict__ invdeg,
                               const float* __restrict__ agg, ushort* __restrict__ hout, int N) {
    int t = blockIdx.x * blockDim.x + threadIdx.x;
    if (t >= N * 16) return;
    int o = t & 15;
    int n = t >> 4;
    const uint4* hp = reinterpret_cast<const uint4*>(hin + (size_t)n * 16);
    uint4 ha = hp[0], hb = hp[1];
    float acc = agg[t] * invdeg[n] + bias[o];
    unsigned dw[8] = {ha.x, ha.y, ha.z, ha.w, hb.x, hb.y, hb.z, hb.w};
    #pragma unroll
    for (int j = 0; j < 8; ++j) {
        h2f p = u2h(dw[j]);
        acc += (float)p[0] * root[(2 * j) * 16 + o] + (float)p[1] * root[(2 * j + 1) * 16 + o];
    }
    hout[t] = __builtin_bit_cast(ushort, (_Float16)fmaxf(acc, 0.0f));
}

extern "C" void kernel_launch(void* const* d_in, const int* in_sizes, int n_in,
                              void* d_out, int out_size, void* d_ws, size_t ws_size,
                              hipStream_t stream) {
    const float* x      = (const float*)d_in[0];
    const int*   eidx   = (const int*)d_in[1];
    const float* eattr  = (const float*)d_in[2];
    const float* W1     = (const float*)d_in[3];
    const float* root1  = (const float*)d_in[4];
    const float* b1     = (const float*)d_in[5];
    const float* W2     = (const float*)d_in[6];
    const float* root2  = (const float*)d_in[7];
    const float* b2     = (const float*)d_in[8];
    const float* W3     = (const float*)d_in[9];
    const float* root3  = (const float*)d_in[10];
    const float* b3     = (const float*)d_in[11];
    const float* fcw    = (const float*)d_in[12];
    const float* fcb    = (const float*)d_in[13];
    float* out = (float*)d_out;

    const int N = in_sizes[0] / 2;
    const int E = in_sizes[2] / 2;
    const int* src = eidx;
    const int* dst = eidx + E;
    const int BT = 256;

    // ---- CSR workspace layout (bytes) ----
    char* w = (char*)d_ws;
    size_t off = 0;
    uint4* epack = (uint4*)(w + off); off += (size_t)E * 16;
    int* offs    = (int*)(w + off);   off += ((size_t)(N + 1)) * 4; off = (off + 15) & ~(size_t)15;
    int* cnt     = (int*)(w + off);   off += (size_t)N * 4;         off = (off + 15) & ~(size_t)15;
    int* cursor  = (int*)(w + off);   off += (size_t)N * 4;         off = (off + 15) & ~(size_t)15;
    int* sums    = (int*)(w + off);   off += SCAN_T * 4;            off = (off + 15) & ~(size_t)15;
    ushort* hH1  = (ushort*)(w + off); off += (size_t)N * 32;
    ushort* hH2  = (ushort*)(w + off); off += (size_t)N * 32;
    size_t need_csr = off;
    int nb = (N + SCAN_E - 1) / SCAN_E;

    if (ws_size >= need_csr && nb <= SCAN_T) {
        // ---- CSR build ----
        hipMemsetAsync(cnt, 0, (size_t)N * 4, stream);
        hipMemsetAsync(cursor, 0, (size_t)N * 4, stream);
        hist_kernel<<<2048, BT, 0, stream>>>(dst, cnt, E);
        scan1_kernel<<<nb, SCAN_T, 0, stream>>>(cnt, offs, sums, N);
        scan2_kernel<<<1, SCAN_T, 0, stream>>>(sums, nb);
        scan3_kernel<<<(N + BT - 1) / BT, BT, 0, stream>>>(offs, sums, N, E);
        scatter_kernel<<<2048, BT, 0, stream>>>(eattr, src, dst, offs, cursor, epack, E);

        // ---- fused layers ----
        int node_grid = (N * 16 + BT - 1) / BT;
        csr2_kernel<<<node_grid, BT, 0, stream>>>(x, epack, offs, W1, root1, b1, hH1, N);
        csr16_kernel<<<node_grid, BT, 0, stream>>>(hH1, epack, offs, W2, root2, b2, hH2, N);
        csr16_kernel<<<node_grid, BT, 0, stream>>>(hH2, epack, offs, W3, root3, b3, hH1, N);
        fc_kernel<<<(N + BT - 1) / BT, BT, 0, stream>>>(hH1, fcw, fcb, out, N);
    } else {
        // ---- fallback: atomic path ----
        float* agg = (float*)d_ws;                       // N*16
        float* deg = agg + (size_t)N * 16;               // N
        size_t f17 = ((size_t)N * 17 + 7) & ~(size_t)7;
        ushort* fH1 = (ushort*)((float*)d_ws + f17);     // N*16 f16
        ushort* fH2 = fH1 + (size_t)N * 16;
        const int EG = 2048;
        int node_grid = (N * 16 + BT - 1) / BT;

        hipMemsetAsync(deg, 0, (size_t)N * 4, stream);
        deg_count_kernel<<<2048, BT, 0, stream>>>(dst, deg, E);
        deg_inv_kernel<<<(N + BT - 1) / BT, BT, 0, stream>>>(deg, N);

        hipMemsetAsync(agg, 0, (size_t)N * 64, stream);
        edge2_fb<<<EG, BT, 0, stream>>>(x, dst, eattr, src, W1, agg, E);
        finalize2h_fb<<<node_grid, BT, 0, stream>>>(x, root1, b1, deg, agg, fH1, N);

        hipMemsetAsync(agg, 0, (size_t)N * 64, stream);
        edge16h_fb<<<EG, BT, 0, stream>>>(fH1, dst, eattr, src, W2, agg, E);
        finalize16h_fb<<<node_grid, BT, 0, stream>>>(fH1, root2, b2, deg, agg, fH2, N);

        hipMemsetAsync(agg, 0, (size_t)N * 64, stream);
        edge16h_fb<<<EG, BT, 0, stream>>>(fH2, dst, eattr, src, W3, agg, E);
        finalize16h_fb<<<node_grid, BT, 0, stream>>>(fH2, root3, b3, deg, agg, fH1, N);

        fc_kernel<<<(N + BT - 1) / BT, BT, 0, stream>>>(fH1, fcw, fcb, out, N);
    }
}